// Round 3
// baseline (597.543 us; speedup 1.0000x reference)
//
#include <hip/hip_runtime.h>

// Tensor-train forward, B=4096 N=8 F=64 D=64 C=10.
// R3: per-CU core-traffic wall (~3.15 MB/block @ ~70 GB/s/CU) diagnosed from
// R1==R2. Fix: K-split (bond r) across block pairs (b, b^8): each block reads
// only its r-half of every core (1.6 MB), partial v exchanged via ws + device
// -scope flag handshake (same-XCD pairing, sentinel-based so 0xAA poison is a
// valid reset). 256 blocks x 512 thr, 32 samples per pair.

typedef _Float16 half8 __attribute__((ext_vector_type(8)));
typedef _Float16 half4 __attribute__((ext_vector_type(4)));
typedef float f32x4 __attribute__((ext_vector_type(4)));

#define LAST_OFF   0          // 8 frag-slots * 512 halves
#define MID_OFF    4096
#define MID_SZ     262144     // per mid core: 512 frag-slots * 512 halves
#define FIRST_OFF  1576960    // 4096 + 6*262144
#define N_FRAGS    3208
#define EX_BYTES   (4u << 20)   // exchange data area (byte offset in ws)
#define FLAG_BYTES (16u << 20)  // flag area (byte offset in ws)

// ---------- prologue: fp32 cores -> f16, MFMA-A-fragment swizzled ----------
// A-frag (16x16x32 f16): lane holds A[m=lane&15][k=(lane>>4)*8 + j], j=0..7.
__global__ __launch_bounds__(256) void tt_swz(
    const float* __restrict__ cf,   // core_first (10,64,64)  [c][p][r]
    const float* __restrict__ cm,   // cores_mid  (6,64,64,64)[ci][l][p][r]
    const float* __restrict__ cl,   // core_last  (64,64)     [l][p]
    _Float16* __restrict__ ws)
{
  int gid = blockIdx.x * 256 + threadIdx.x;
  if (gid >= N_FRAGS * 64) return;
  int lane = gid & 63, frag = gid >> 6;
  int quad = lane >> 4, m16 = lane & 15;
  half8 hv;
  _Float16* dst;
  if (frag < 8) {                       // core_last: rows l (4 tiles), k = p
    int t = frag >> 1, kt = frag & 1;
    int l = t * 16 + m16;
    const float* s = cl + l * 64 + kt * 32 + quad * 8;
#pragma unroll
    for (int j = 0; j < 8; ++j) hv[j] = (_Float16)s[j];
    dst = ws + LAST_OFF + (size_t)((t * 2 + kt) * 64 + lane) * 8;
  } else if (frag < 8 + 3072) {         // mid cores: rows (p,l), k = r
    int f2 = frag - 8;
    int ci = f2 >> 9, rem = f2 & 511;
    int t = rem >> 1, kt = rem & 1;
    int l = (t & 3) * 16 + m16, p = t >> 2;
    const float* s = cm + (((size_t)ci * 64 + l) * 64 + p) * 64 + kt * 32 + quad * 8;
#pragma unroll
    for (int j = 0; j < 8; ++j) hv[j] = (_Float16)s[j];
    dst = ws + MID_OFF + (size_t)ci * MID_SZ + (size_t)(rem * 64 + lane) * 8;
  } else {                              // core_first: rows c (pad 16), k = r
    int f2 = frag - 3080;
    int t = f2 >> 1, kt = f2 & 1;
    int c = m16, p = t;
    if (c < 10) {
      const float* s = cf + ((size_t)(c * 64 + p)) * 64 + kt * 32 + quad * 8;
#pragma unroll
      for (int j = 0; j < 8; ++j) hv[j] = (_Float16)s[j];
    } else {
#pragma unroll
      for (int j = 0; j < 8; ++j) hv[j] = (_Float16)0.f;
    }
    dst = ws + FIRST_OFF + (size_t)((t * 2 + kt) * 64 + lane) * 8;
  }
  *(half8*)dst = hv;
}

// ------------------- main chain: 256 blocks x 512 threads ------------------
__global__ __launch_bounds__(512) void tt_main(
    const float* __restrict__ x,        // (4096, 8, 64)
    _Float16* __restrict__ ws,
    float* __restrict__ out)            // (4096, 10)
{
  __shared__ __align__(16) _Float16 Xs[512][34];     // [n*64+p][s] f16
  __shared__ __align__(16) _Float16 Vt[2][32][72];   // p-partials [part][s][l]
  __shared__ __align__(16) _Float16 Vc[32][72];      // combined full v [s][r]
  __shared__ __align__(16) float Red[8][10][32];     // final per-wave partials
  const int tid = threadIdx.x;
  const int w = tid >> 6, lane = tid & 63;
  const int quad = lane >> 4, sl = lane & 15;
  const int b = blockIdx.x;
  const int h = (b >> 3) & 1;                        // my r-half
  const int gid = (b & 7) + ((b >> 4) << 3);         // sample group 0..127

  char* exbase = (char*)ws + EX_BYTES;
  unsigned* flbase = (unsigned*)((char*)ws + FLAG_BYTES);

  // ---- stage x for the group's 32 samples (f32 -> f16, transposed) ----
  {
    const float* xb = x + (size_t)gid * 32 * 512;
    int s = tid >> 4, ch = tid & 15;
#pragma unroll
    for (int k = 0; k < 8; ++k) {
      int f4 = ch + 16 * k;
      float4 v = *(const float4*)(xb + (size_t)s * 512 + (size_t)f4 * 4);
      int row = f4 * 4;
      Xs[row + 0][s] = (_Float16)v.x;
      Xs[row + 1][s] = (_Float16)v.y;
      Xs[row + 2][s] = (_Float16)v.z;
      Xs[row + 3][s] = (_Float16)v.w;
    }
  }
  __syncthreads();

  // ---- GEMM1 (core_last, tiny): both blocks compute full v7 redundantly ----
  {
    int st = w >> 2, tt = w & 3;                     // 8 waves = 2 stiles x 4 ltiles
    half8 b0, b1;
#pragma unroll
    for (int j = 0; j < 8; ++j) {
      b0[j] = Xs[448 + quad * 8 + j][st * 16 + sl];
      b1[j] = Xs[448 + 32 + quad * 8 + j][st * 16 + sl];
    }
    half8 a0 = *(const half8*)(ws + LAST_OFF + (size_t)((tt * 2 + 0) * 64 + lane) * 8);
    half8 a1 = *(const half8*)(ws + LAST_OFF + (size_t)((tt * 2 + 1) * 64 + lane) * 8);
    f32x4 d = {0.f, 0.f, 0.f, 0.f};
    d = __builtin_amdgcn_mfma_f32_16x16x32_f16(a0, b0, d, 0, 0, 0);
    d = __builtin_amdgcn_mfma_f32_16x16x32_f16(a1, b1, d, 0, 0, 0);
    half4 hv;
#pragma unroll
    for (int r = 0; r < 4; ++r) hv[r] = (_Float16)d[r];
    *(half4*)&Vc[st * 16 + sl][tt * 16 + quad * 4] = hv;
  }
  __syncthreads();

  const int part = w >> 2;                           // p-parity partial id
  // ---- 6 middle steps (cores_mid[5] .. cores_mid[0]), r-half h only ----
  for (int step = 0; step < 6; ++step) {
    int ci = 5 - step;
    half8 bA = *(const half8*)&Vc[sl][h * 32 + quad * 8];        // samples sl
    half8 bB = *(const half8*)&Vc[16 + sl][h * 32 + quad * 8];   // samples 16+sl
    const _Float16* wl = ws + MID_OFF + (size_t)ci * MID_SZ
                       + (size_t)((w * 2 + h) * 64 + lane) * 8;
    float c00 = 0.f, c01 = 0.f, c02 = 0.f, c03 = 0.f;
    float c10 = 0.f, c11 = 0.f, c12 = 0.f, c13 = 0.f;
    const int xrow = (ci + 1) * 64;
#pragma unroll 8
    for (int j = 0; j < 32; ++j) {
      int t = 8 * j + w;                             // tile: p=t>>2, lch=(w&3)*16
      int p = t >> 2;
      half8 A = *(const half8*)(wl + (size_t)j * 8192);
      f32x4 d0 = {0.f, 0.f, 0.f, 0.f}, d1 = {0.f, 0.f, 0.f, 0.f};
      d0 = __builtin_amdgcn_mfma_f32_16x16x32_f16(A, bA, d0, 0, 0, 0);
      d1 = __builtin_amdgcn_mfma_f32_16x16x32_f16(A, bB, d1, 0, 0, 0);
      float xv0 = (float)Xs[xrow + p][sl];
      float xv1 = (float)Xs[xrow + p][16 + sl];
      c00 += xv0 * d0[0]; c01 += xv0 * d0[1]; c02 += xv0 * d0[2]; c03 += xv0 * d0[3];
      c10 += xv1 * d1[0]; c11 += xv1 * d1[1]; c12 += xv1 * d1[2]; c13 += xv1 * d1[3];
    }
    {
      int lch = (w & 3) * 16;
      half4 h0, h1;
      h0[0] = (_Float16)c00; h0[1] = (_Float16)c01; h0[2] = (_Float16)c02; h0[3] = (_Float16)c03;
      h1[0] = (_Float16)c10; h1[1] = (_Float16)c11; h1[2] = (_Float16)c12; h1[3] = (_Float16)c13;
      *(half4*)&Vt[part][sl][lch + quad * 4] = h0;
      *(half4*)&Vt[part][16 + sl][lch + quad * 4] = h1;
    }
    __syncthreads();
    // ---- combine local p-partials, exchange r-half partial with partner ----
    {
      int s = tid >> 4, r0 = (tid & 15) * 4;
      half4 p0 = *(const half4*)&Vt[0][s][r0];
      half4 p1 = *(const half4*)&Vt[1][s][r0];
      float l0 = (float)p0[0] + (float)p1[0];
      float l1 = (float)p0[1] + (float)p1[1];
      float l2 = (float)p0[2] + (float)p1[2];
      float l3 = (float)p0[3] + (float)p1[3];
      half4 hv;
      hv[0] = (_Float16)l0; hv[1] = (_Float16)l1;
      hv[2] = (_Float16)l2; hv[3] = (_Float16)l3;
      char* mine = exbase + (size_t)(((gid * 7 + step) * 2 + h)) * 4096;
      char* theirs = exbase + (size_t)(((gid * 7 + step) * 2 + (1 - h))) * 4096;
      *(half4*)(mine + (size_t)(s * 64 + r0) * 2) = hv;
      __threadfence();
      __syncthreads();
      unsigned want = 0x5EED0C00u + (unsigned)step;
      unsigned* myf = flbase + ((gid * 7 + step) * 2 + h) * 16;
      unsigned* pf  = flbase + ((gid * 7 + step) * 2 + (1 - h)) * 16;
      if (tid == 0) {
        __hip_atomic_store(myf, want, __ATOMIC_RELEASE, __HIP_MEMORY_SCOPE_AGENT);
        while (__hip_atomic_load(pf, __ATOMIC_ACQUIRE, __HIP_MEMORY_SCOPE_AGENT) != want)
          __builtin_amdgcn_s_sleep(2);
      }
      __syncthreads();
      __threadfence();
      half4 rm = *(const half4*)(theirs + (size_t)(s * 64 + r0) * 2);
      half4 fv;
      fv[0] = (_Float16)(l0 + (float)rm[0]);
      fv[1] = (_Float16)(l1 + (float)rm[1]);
      fv[2] = (_Float16)(l2 + (float)rm[2]);
      fv[3] = (_Float16)(l3 + (float)rm[3]);
      *(half4*)&Vc[s][r0] = fv;
    }
    __syncthreads();
  }

  // ---- final (core_first): r-half h, partial out exchanged, h=0 writes ----
  {
    half8 bA = *(const half8*)&Vc[sl][h * 32 + quad * 8];
    half8 bB = *(const half8*)&Vc[16 + sl][h * 32 + quad * 8];
    float f00 = 0.f, f01 = 0.f, f02 = 0.f, f03 = 0.f;
    float f10 = 0.f, f11 = 0.f, f12 = 0.f, f13 = 0.f;
#pragma unroll
    for (int j = 0; j < 8; ++j) {
      int t = j * 8 + w;                             // t = p
      half8 A = *(const half8*)(ws + FIRST_OFF + (size_t)((t * 2 + h) * 64 + lane) * 8);
      f32x4 d0 = {0.f, 0.f, 0.f, 0.f}, d1 = {0.f, 0.f, 0.f, 0.f};
      d0 = __builtin_amdgcn_mfma_f32_16x16x32_f16(A, bA, d0, 0, 0, 0);
      d1 = __builtin_amdgcn_mfma_f32_16x16x32_f16(A, bB, d1, 0, 0, 0);
      float xv0 = (float)Xs[t][sl];
      float xv1 = (float)Xs[t][16 + sl];
      f00 += xv0 * d0[0]; f01 += xv0 * d0[1]; f02 += xv0 * d0[2]; f03 += xv0 * d0[3];
      f10 += xv1 * d1[0]; f11 += xv1 * d1[1]; f12 += xv1 * d1[2]; f13 += xv1 * d1[3];
    }
    float a0[4] = {f00, f01, f02, f03};
    float a1[4] = {f10, f11, f12, f13};
#pragma unroll
    for (int r = 0; r < 4; ++r) {
      int c = quad * 4 + r;
      if (c < 10) {
        Red[w][c][sl] = a0[r];
        Red[w][c][16 + sl] = a1[r];
      }
    }
  }
  __syncthreads();
  {
    char* mine = exbase + (size_t)(((gid * 7 + 6) * 2 + h)) * 4096;
    char* theirs = exbase + (size_t)(((gid * 7 + 6) * 2 + (1 - h))) * 4096;
    float val = 0.f;
    int c = tid >> 5, s = tid & 31;
    if (tid < 320) {
#pragma unroll
      for (int ww = 0; ww < 8; ++ww) val += Red[ww][c][s];
      *(float*)(mine + (size_t)(c * 32 + s) * 4) = val;
    }
    __threadfence();
    __syncthreads();
    unsigned want = 0x5EED0C06u;
    unsigned* myf = flbase + ((gid * 7 + 6) * 2 + h) * 16;
    unsigned* pf  = flbase + ((gid * 7 + 6) * 2 + (1 - h)) * 16;
    if (h == 1) {
      if (tid == 0)
        __hip_atomic_store(myf, want, __ATOMIC_RELEASE, __HIP_MEMORY_SCOPE_AGENT);
      return;
    }
    if (tid == 0) {
      while (__hip_atomic_load(pf, __ATOMIC_ACQUIRE, __HIP_MEMORY_SCOPE_AGENT) != want)
        __builtin_amdgcn_s_sleep(2);
    }
    __syncthreads();
    __threadfence();
    if (tid < 320) {
      float rm = *(const float*)(theirs + (size_t)(c * 32 + s) * 4);
      out[((size_t)gid * 32 + s) * 10 + c] = val + rm;
    }
  }
}

extern "C" void kernel_launch(void* const* d_in, const int* in_sizes, int n_in,
                              void* d_out, int out_size, void* d_ws, size_t ws_size,
                              hipStream_t stream) {
  const float* x  = (const float*)d_in[0];   // (4096,8,64)
  const float* cf = (const float*)d_in[1];   // (10,64,64)
  const float* cm = (const float*)d_in[2];   // (6,64,64,64)
  const float* cl = (const float*)d_in[3];   // (64,64)
  _Float16* ws = (_Float16*)d_ws;            // cores + exchange + flags (<17 MB)
  float* out = (float*)d_out;
  tt_swz<<<dim3((N_FRAGS * 64 + 255) / 256), dim3(256), 0, stream>>>(cf, cm, cl, ws);
  tt_main<<<dim3(256), dim3(512), 0, stream>>>(x, ws, out);
}

// Round 4
// 131.781 us; speedup vs baseline: 4.5344x; 4.5344x over previous
//
#include <hip/hip_runtime.h>

// Tensor-train forward, B=4096 N=8 F=64 D=64 C=10.
// R4: back to R1 shape (256 blocks x 512 thr, 16 samples/block, no cross-block
// traffic). VALU-slimmed inner loop: x preloaded to registers per step via a
// parity-split transposed LDS layout (4x ds_read_b128 per wave per step,
// static extraction) instead of per-iter ds_read_u16. Target: pure A-load wall.

typedef _Float16 half8 __attribute__((ext_vector_type(8)));
typedef _Float16 half4 __attribute__((ext_vector_type(4)));
typedef _Float16 half2v __attribute__((ext_vector_type(2)));
typedef float f32x4 __attribute__((ext_vector_type(4)));

#define LAST_OFF   0          // 8 frag-slots * 512 halves
#define MID_OFF    4096
#define MID_SZ     262144     // per mid core: 512 frag-slots * 512 halves
#define FIRST_OFF  1576960    // 4096 + 6*262144
#define N_FRAGS    3208

// ---------- prologue: fp32 cores -> f16, MFMA-A-fragment swizzled ----------
// A-frag (16x16x32 f16): lane holds A[m=lane&15][k=(lane>>4)*8 + j], j=0..7.
__global__ __launch_bounds__(256) void tt_swz(
    const float* __restrict__ cf,   // core_first (10,64,64)  [c][p][r]
    const float* __restrict__ cm,   // cores_mid  (6,64,64,64)[ci][l][p][r]
    const float* __restrict__ cl,   // core_last  (64,64)     [l][p]
    _Float16* __restrict__ ws)
{
  int gid = blockIdx.x * 256 + threadIdx.x;
  if (gid >= N_FRAGS * 64) return;
  int lane = gid & 63, frag = gid >> 6;
  int quad = lane >> 4, m16 = lane & 15;
  half8 hv;
  _Float16* dst;
  if (frag < 8) {                       // core_last: rows l (4 tiles), k = p
    int t = frag >> 1, kt = frag & 1;
    int l = t * 16 + m16;
    const float* s = cl + l * 64 + kt * 32 + quad * 8;
#pragma unroll
    for (int j = 0; j < 8; ++j) hv[j] = (_Float16)s[j];
    dst = ws + LAST_OFF + (size_t)((t * 2 + kt) * 64 + lane) * 8;
  } else if (frag < 8 + 3072) {         // mid cores: rows (p,l), k = r
    int f2 = frag - 8;
    int ci = f2 >> 9, rem = f2 & 511;
    int t = rem >> 1, kt = rem & 1;
    int l = (t & 3) * 16 + m16, p = t >> 2;
    const float* s = cm + (((size_t)ci * 64 + l) * 64 + p) * 64 + kt * 32 + quad * 8;
#pragma unroll
    for (int j = 0; j < 8; ++j) hv[j] = (_Float16)s[j];
    dst = ws + MID_OFF + (size_t)ci * MID_SZ + (size_t)(rem * 64 + lane) * 8;
  } else {                              // core_first: rows c (pad 16), k = r
    int f2 = frag - 3080;
    int t = f2 >> 1, kt = f2 & 1;
    int c = m16, p = t;
    if (c < 10) {
      const float* s = cf + ((size_t)(c * 64 + p)) * 64 + kt * 32 + quad * 8;
#pragma unroll
      for (int j = 0; j < 8; ++j) hv[j] = (_Float16)s[j];
    } else {
#pragma unroll
      for (int j = 0; j < 8; ++j) hv[j] = (_Float16)0.f;
    }
    dst = ws + FIRST_OFF + (size_t)((t * 2 + kt) * 64 + lane) * 8;
  }
  *(half8*)dst = hv;
}

// ------------------- main chain: 256 blocks x 512 threads ------------------
__global__ __launch_bounds__(512) void tt_main(
    const float* __restrict__ x,        // (4096, 8, 64)
    const _Float16* __restrict__ ws,
    float* __restrict__ out)            // (4096, 10)
{
  // XT[s][n*80 + par*40 + (p>>1)] : parity-split transposed x, f16.
  // row stride 648 halves = 1296 B = 324 words == 4 mod 32 -> 2-way max.
  __shared__ __align__(16) _Float16 XT[16][648];
  __shared__ __align__(16) _Float16 Vt[2][16][72];   // v partials [part][s][l]
  __shared__ __align__(16) float Red[8][16][16];     // final per-wave partials
  const int tid = threadIdx.x;
  const int w = tid >> 6, lane = tid & 63;
  const int quad = lane >> 4, sl = lane & 15;
  const int blk = blockIdx.x;

  // ---- stage x (16 samples x 512 floats -> f16, parity-split transpose) ----
  {
    const float* xb = x + (size_t)blk * 16 * 512;
    int s = tid >> 5, q = tid & 31;
#pragma unroll
    for (int k = 0; k < 4; ++k) {
      int f4 = q + 32 * k;                       // float4 index 0..127
      float4 v = *(const float4*)(xb + (size_t)s * 512 + (size_t)f4 * 4);
      int n = f4 >> 4, i2 = (f4 & 15) * 2;
      _Float16* row = &XT[s][n * 80];
      half2v e0; e0[0] = (_Float16)v.x; e0[1] = (_Float16)v.z;
      half2v e1; e1[0] = (_Float16)v.y; e1[1] = (_Float16)v.w;
      *(half2v*)&row[i2] = e0;                   // even p
      *(half2v*)&row[40 + i2] = e1;              // odd p
    }
  }
  __syncthreads();

  // ---- GEMM1 (core_last): 8 wave-tasks = (kt = w>>2, tt = w&3) ----
  {
    int tt = w & 3, kt = w >> 2;
    const _Float16* r7 = &XT[sl][7 * 80];
    half4 e0 = *(const half4*)&r7[kt * 16 + quad * 4];        // even p
    half4 e1 = *(const half4*)&r7[40 + kt * 16 + quad * 4];   // odd p
    half8 b;
#pragma unroll
    for (int i = 0; i < 4; ++i) { b[2 * i] = e0[i]; b[2 * i + 1] = e1[i]; }
    half8 a = *(const half8*)(ws + LAST_OFF + (size_t)((tt * 2 + kt) * 64 + lane) * 8);
    f32x4 d = {0.f, 0.f, 0.f, 0.f};
    d = __builtin_amdgcn_mfma_f32_16x16x32_f16(a, b, d, 0, 0, 0);
    half4 hv;
#pragma unroll
    for (int r = 0; r < 4; ++r) hv[r] = (_Float16)d[r];
    *(half4*)&Vt[kt][sl][tt * 16 + quad * 4] = hv;
  }
  __syncthreads();

  const int pr = w >> 2;                 // my p-parity (also Vt partial id)
  const int lch = (w & 3) * 16;
  // ---- 6 middle steps (cores_mid[5] .. cores_mid[0]) ----
  for (int step = 0; step < 6; ++step) {
    int ci = 5 - step;
    // B-frags: v[r][s] = sum of the two p-parity partials
    half8 b0 = *(const half8*)&Vt[0][sl][quad * 8];
    half8 b0b = *(const half8*)&Vt[1][sl][quad * 8];
    half8 b1 = *(const half8*)&Vt[0][sl][32 + quad * 8];
    half8 b1b = *(const half8*)&Vt[1][sl][32 + quad * 8];
    b0 = b0 + b0b; b1 = b1 + b1b;
    // x preload for this step: 32 halves of parity pr (p = 2j + pr, j=0..31)
    const _Float16* xrow = &XT[sl][(ci + 1) * 80 + pr * 40];
    half8 xr0 = *(const half8*)&xrow[0];
    half8 xr1 = *(const half8*)&xrow[8];
    half8 xr2 = *(const half8*)&xrow[16];
    half8 xr3 = *(const half8*)&xrow[24];
    __syncthreads();                     // Vt reads done before overwrite
    float a0 = 0.f, a1 = 0.f, a2 = 0.f, a3 = 0.f;
    const _Float16* wl = ws + MID_OFF + (size_t)ci * MID_SZ
                       + (size_t)w * 1024 + (size_t)lane * 8;
#pragma unroll
    for (int j = 0; j < 32; ++j) {
      const _Float16* fp = wl + (size_t)j * 8192;     // tile t = 8j + w
      half8 A0 = *(const half8*)fp;
      half8 A1 = *(const half8*)(fp + 512);
      f32x4 dd = {0.f, 0.f, 0.f, 0.f};
      dd = __builtin_amdgcn_mfma_f32_16x16x32_f16(A0, b0, dd, 0, 0, 0);
      dd = __builtin_amdgcn_mfma_f32_16x16x32_f16(A1, b1, dd, 0, 0, 0);
      float xv;
      if (j < 8)       xv = (float)xr0[j];
      else if (j < 16) xv = (float)xr1[j - 8];
      else if (j < 24) xv = (float)xr2[j - 16];
      else             xv = (float)xr3[j - 24];
      a0 += xv * dd[0]; a1 += xv * dd[1]; a2 += xv * dd[2]; a3 += xv * dd[3];
    }
    half4 hv;
    hv[0] = (_Float16)a0; hv[1] = (_Float16)a1;
    hv[2] = (_Float16)a2; hv[3] = (_Float16)a3;
    *(half4*)&Vt[pr][sl][lch + quad * 4] = hv;
    __syncthreads();
  }

  // ---- final (core_first): 8 waves x 8 p-tiles each ----
  {
    half8 b0 = *(const half8*)&Vt[0][sl][quad * 8];
    half8 b0b = *(const half8*)&Vt[1][sl][quad * 8];
    half8 b1 = *(const half8*)&Vt[0][sl][32 + quad * 8];
    half8 b1b = *(const half8*)&Vt[1][sl][32 + quad * 8];
    b0 = b0 + b0b; b1 = b1 + b1b;
    float f0 = 0.f, f1 = 0.f, f2 = 0.f, f3 = 0.f;
    const int fpar = w & 1, fbase = w >> 1;
#pragma unroll
    for (int j = 0; j < 8; ++j) {
      int t = j * 8 + w;                              // t = p
      const _Float16* fp = ws + FIRST_OFF + (size_t)t * 1024 + (size_t)lane * 8;
      half8 A0 = *(const half8*)fp;
      half8 A1 = *(const half8*)(fp + 512);
      f32x4 dd = {0.f, 0.f, 0.f, 0.f};
      dd = __builtin_amdgcn_mfma_f32_16x16x32_f16(A0, b0, dd, 0, 0, 0);
      dd = __builtin_amdgcn_mfma_f32_16x16x32_f16(A1, b1, dd, 0, 0, 0);
      float xv = (float)XT[sl][fpar * 40 + 4 * j + fbase];   // x[s,0,p=t]
      f0 += xv * dd[0]; f1 += xv * dd[1]; f2 += xv * dd[2]; f3 += xv * dd[3];
    }
    Red[w][quad * 4 + 0][sl] = f0;
    Red[w][quad * 4 + 1][sl] = f1;
    Red[w][quad * 4 + 2][sl] = f2;
    Red[w][quad * 4 + 3][sl] = f3;
  }
  __syncthreads();
  if (tid < 256) {
    int c = tid >> 4, s = tid & 15;
    if (c < 10) {
      float sum = 0.f;
#pragma unroll
      for (int ww = 0; ww < 8; ++ww) sum += Red[ww][c][s];
      out[((size_t)blk * 16 + s) * 10 + c] = sum;
    }
  }
}

extern "C" void kernel_launch(void* const* d_in, const int* in_sizes, int n_in,
                              void* d_out, int out_size, void* d_ws, size_t ws_size,
                              hipStream_t stream) {
  const float* x  = (const float*)d_in[0];   // (4096,8,64)
  const float* cf = (const float*)d_in[1];   // (10,64,64)
  const float* cm = (const float*)d_in[2];   // (6,64,64,64)
  const float* cl = (const float*)d_in[3];   // (64,64)
  _Float16* ws = (_Float16*)d_ws;            // ~3.3 MB used
  float* out = (float*)d_out;
  tt_swz<<<dim3((N_FRAGS * 64 + 255) / 256), dim3(256), 0, stream>>>(cf, cm, cl, ws);
  tt_main<<<dim3(256), dim3(512), 0, stream>>>(x, ws, out);
}